// Round 1
// baseline (12010.653 us; speedup 1.0000x reference)
//
#include <hip/hip_runtime.h>
#include <hip/hip_bf16.h>
#include <math.h>

#define S_LEN 128
#define BATCH 32
#define HID   1024
#define VOCAB 32000
#define G4    4096   // 4*HID

// ---------------- embedding gather: e[m][k] = emb[x[m]][k], m = s*32+b ----------------
__global__ __launch_bounds__(256)
void embed_kernel(const int* __restrict__ x, const float* __restrict__ emb,
                  float* __restrict__ e) {
    int idx = blockIdx.x * 256 + threadIdx.x;     // one float4 per thread
    int m  = idx >> 8;                            // 256 float4 per row of 1024
    int k4 = (idx & 255) << 2;
    int row = x[m];
    *(float4*)&e[(size_t)m * HID + k4] = *(const float4*)&emb[(size_t)row * HID + k4];
}

// ---------------- generic NT GEMM: C[m][n] = dot(A[m,:], B[n,:]) + bias ----------------
// A: [M,K] row-major, Bm: [N,K] row-major. BM=128, BN=64, KC=16, 256 threads, 8x4/thread.
// TSTORE==0: C row-major [M,N].  TSTORE==1: C = gxT layout [(m>>5)][n][m&31] (i.e. [S][4H][B]).
template<int TSTORE>
__global__ __launch_bounds__(256)
void gemm_nt(const float* __restrict__ A, const float* __restrict__ Bm,
             const float* __restrict__ bias1, const float* __restrict__ bias2,
             float* __restrict__ C, int M, int N, int K) {
    __shared__ float As[16][128];
    __shared__ float Bs[16][64];
    const int t  = threadIdx.x;
    const int m0 = blockIdx.y * 128;
    const int n0 = blockIdx.x * 64;
    const int tx = t & 15, ty = t >> 4;

    float acc[8][4];
#pragma unroll
    for (int i = 0; i < 8; ++i)
#pragma unroll
        for (int j = 0; j < 4; ++j) acc[i][j] = 0.f;

    for (int kc = 0; kc < K; kc += 16) {
        // stage A tile: 128x16 = 512 float4, 2 per thread
#pragma unroll
        for (int s2 = 0; s2 < 2; ++s2) {
            int s = t * 2 + s2;
            int row = s >> 2, kslot = (s & 3) * 4;
            float4 v = *(const float4*)&A[(size_t)(m0 + row) * K + kc + kslot];
            As[kslot + 0][row] = v.x; As[kslot + 1][row] = v.y;
            As[kslot + 2][row] = v.z; As[kslot + 3][row] = v.w;
        }
        // stage B tile: 64x16 = 256 float4, 1 per thread
        {
            int row = t >> 2, kslot = (t & 3) * 4;
            float4 v = *(const float4*)&Bm[(size_t)(n0 + row) * K + kc + kslot];
            Bs[kslot + 0][row] = v.x; Bs[kslot + 1][row] = v.y;
            Bs[kslot + 2][row] = v.z; Bs[kslot + 3][row] = v.w;
        }
        __syncthreads();
#pragma unroll
        for (int k = 0; k < 16; ++k) {
            float4 a0 = *(const float4*)&As[k][ty * 8];
            float4 a1 = *(const float4*)&As[k][ty * 8 + 4];
            float4 b0 = *(const float4*)&Bs[k][tx * 4];
            float am[8] = {a0.x, a0.y, a0.z, a0.w, a1.x, a1.y, a1.z, a1.w};
            float bn[4] = {b0.x, b0.y, b0.z, b0.w};
#pragma unroll
            for (int i = 0; i < 8; ++i)
#pragma unroll
                for (int j = 0; j < 4; ++j) acc[i][j] += am[i] * bn[j];
        }
        __syncthreads();
    }

    float bb[4];
#pragma unroll
    for (int j = 0; j < 4; ++j) {
        int n = n0 + tx * 4 + j;
        bb[j] = bias1[n] + (bias2 ? bias2[n] : 0.f);
    }

    if (TSTORE == 0) {
#pragma unroll
        for (int i = 0; i < 8; ++i) {
            int m = m0 + ty * 8 + i;
            float4 v = make_float4(acc[i][0] + bb[0], acc[i][1] + bb[1],
                                   acc[i][2] + bb[2], acc[i][3] + bb[3]);
            *(float4*)&C[(size_t)m * N + n0 + tx * 4] = v;
        }
    } else {
#pragma unroll
        for (int i = 0; i < 8; ++i) {
            int m = m0 + ty * 8 + i;
            int s = m >> 5, b = m & 31;
#pragma unroll
            for (int j = 0; j < 4; ++j) {
                int n = n0 + tx * 4 + j;
                C[((size_t)s * G4 + n) * 32 + b] = acc[i][j] + bb[j];
            }
        }
    }
}

// ---------------- state init / save (transpose to/from hT[k][b]) ----------------
__global__ __launch_bounds__(256)
void init_state(const float* __restrict__ h0, const float* __restrict__ c0,
                float* __restrict__ hT, float* __restrict__ cT) {
    int t = blockIdx.x * 256 + threadIdx.x;   // t = j*32+b
    int j = t >> 5, b = t & 31;
    hT[t] = h0[b * HID + j];
    cT[t] = c0[b * HID + j];
}

__global__ __launch_bounds__(256)
void save_state(const float* __restrict__ hT, const float* __restrict__ cT,
                float* __restrict__ out_h, float* __restrict__ out_c) {
    int t = blockIdx.x * 256 + threadIdx.x;
    int j = t >> 5, b = t & 31;
    out_h[b * HID + j] = hT[t];
    out_c[b * HID + j] = cT[t];
}

// ---------------- one LSTM timestep ----------------
// gxT: [4H][B] for this step.  Whh: [4H][H].  hT_in/hT_out/cT: [H][B] transposed.
// y_out: [B][H] for this step.  Block = 4 hidden indices (all 4 gates, all 32 b).
__global__ __launch_bounds__(256)
void lstm_step(const float* __restrict__ gxT, const float* __restrict__ Whh,
               const float* __restrict__ hT_in, float* __restrict__ hT_out,
               float* __restrict__ cT, float* __restrict__ y_out) {
    __shared__ float gbuf[16][32];
    const int t = threadIdx.x;
    const int b = t & 31, slot = t >> 5;          // slot 0..7
    const int j0 = blockIdx.x * 4;
    const int r1 = slot, r2 = slot + 8;           // 16 rows = 4 gates x 4 j
    const int n1 = (r1 >> 2) * HID + j0 + (r1 & 3);
    const int n2 = (r2 >> 2) * HID + j0 + (r2 & 3);
    const float* __restrict__ w1 = &Whh[(size_t)n1 * HID];
    const float* __restrict__ w2 = &Whh[(size_t)n2 * HID];

    float acc1 = 0.f, acc2 = 0.f;
#pragma unroll 4
    for (int k = 0; k < HID; k += 4) {
        float4 a  = *(const float4*)&w1[k];
        float4 c4 = *(const float4*)&w2[k];
        float h0v = hT_in[(k + 0) * 32 + b];
        float h1v = hT_in[(k + 1) * 32 + b];
        float h2v = hT_in[(k + 2) * 32 + b];
        float h3v = hT_in[(k + 3) * 32 + b];
        acc1 += a.x * h0v + a.y * h1v + a.z * h2v + a.w * h3v;
        acc2 += c4.x * h0v + c4.y * h1v + c4.z * h2v + c4.w * h3v;
    }
    gbuf[r1][b] = acc1 + gxT[(size_t)n1 * 32 + b];
    gbuf[r2][b] = acc2 + gxT[(size_t)n2 * 32 + b];
    __syncthreads();

    if (t < 128) {
        int jj = t >> 5;                           // 0..3
        int j = j0 + jj;
        float iv = gbuf[jj][b];
        float fv = gbuf[4 + jj][b];
        float gv = gbuf[8 + jj][b];
        float ov = gbuf[12 + jj][b];
        float si = 1.f / (1.f + expf(-iv));
        float sf = 1.f / (1.f + expf(-fv));
        float so = 1.f / (1.f + expf(-ov));
        float c_old = cT[j * 32 + b];
        float c_new = sf * c_old + si * tanhf(gv);
        float h_new = so * tanhf(c_new);
        cT[j * 32 + b]     = c_new;
        hT_out[j * 32 + b] = h_new;
        y_out[b * HID + j] = h_new;
    }
}

// ---------------- host ----------------
extern "C" void kernel_launch(void* const* d_in, const int* in_sizes, int n_in,
                              void* d_out, int out_size, void* d_ws, size_t ws_size,
                              hipStream_t stream) {
    const int*   x    = (const int*)d_in[0];
    const float* h0_1 = (const float*)d_in[1];
    const float* c0_1 = (const float*)d_in[2];
    const float* h0_2 = (const float*)d_in[3];
    const float* c0_2 = (const float*)d_in[4];
    const float* emb  = (const float*)d_in[5];
    const float* Wih1 = (const float*)d_in[6];
    const float* Whh1 = (const float*)d_in[7];
    const float* bih1 = (const float*)d_in[8];
    const float* bhh1 = (const float*)d_in[9];
    const float* Wih2 = (const float*)d_in[10];
    const float* Whh2 = (const float*)d_in[11];
    const float* bih2 = (const float*)d_in[12];
    const float* bhh2 = (const float*)d_in[13];
    const float* Wlin = (const float*)d_in[14];
    const float* blin = (const float*)d_in[15];

    float* out = (float*)d_out;
    const int M = S_LEN * BATCH;                 // 4096
    float* logits = out;                         // [M][VOCAB]
    float* out_h1 = out + (size_t)M * VOCAB;
    float* out_c1 = out_h1 + BATCH * HID;
    float* out_h2 = out_c1 + BATCH * HID;
    float* out_c2 = out_h2 + BATCH * HID;

    // Scratch carved out of d_out's logits region (fully overwritten by the final GEMM):
    float* gxT = out;                            // [S][4H][B] = 16,777,216 floats
    float* e   = out + 16777216;                 // [M][H]     =  4,194,304 floats
    float* y1  = out + 16777216 + 4194304;       // [M][H]
    // y2 is read WHILE the logits GEMM writes d_out -> must live in d_ws.
    float* y2  = (float*)d_ws;                   // [M][H]
    float* hT0 = y2 + 4194304;                   // [H][B]
    float* hT1 = hT0 + BATCH * HID;
    float* cT  = hT1 + BATCH * HID;

    // 1. embedding
    embed_kernel<<<(M * HID / 4) / 256, 256, 0, stream>>>(x, emb, e);

    // 2. gx1 = e @ Wih1^T + bih1 + bhh1  (transposed store)
    gemm_nt<1><<<dim3(G4 / 64, M / 128), 256, 0, stream>>>(e, Wih1, bih1, bhh1, gxT, M, G4, HID);

    // 3. layer-1 scan
    init_state<<<BATCH * HID / 256, 256, 0, stream>>>(h0_1, c0_1, hT0, cT);
    for (int t = 0; t < S_LEN; ++t) {
        float* hin  = (t & 1) ? hT1 : hT0;
        float* hout = (t & 1) ? hT0 : hT1;
        lstm_step<<<HID / 4, 256, 0, stream>>>(gxT + (size_t)t * G4 * BATCH, Whh1,
                                               hin, hout, cT, y1 + (size_t)t * BATCH * HID);
    }
    save_state<<<BATCH * HID / 256, 256, 0, stream>>>(hT0, cT, out_h1, out_c1);  // 128 even -> final in hT0

    // 4. gx2 = y1 @ Wih2^T + bih2 + bhh2
    gemm_nt<1><<<dim3(G4 / 64, M / 128), 256, 0, stream>>>(y1, Wih2, bih2, bhh2, gxT, M, G4, HID);

    // 5. layer-2 scan
    init_state<<<BATCH * HID / 256, 256, 0, stream>>>(h0_2, c0_2, hT0, cT);
    for (int t = 0; t < S_LEN; ++t) {
        float* hin  = (t & 1) ? hT1 : hT0;
        float* hout = (t & 1) ? hT0 : hT1;
        lstm_step<<<HID / 4, 256, 0, stream>>>(gxT + (size_t)t * G4 * BATCH, Whh2,
                                               hin, hout, cT, y2 + (size_t)t * BATCH * HID);
    }
    save_state<<<BATCH * HID / 256, 256, 0, stream>>>(hT0, cT, out_h2, out_c2);

    // 6. logits = y2 @ Wlin^T + blin  (row-major store, overwrites all scratch in d_out)
    gemm_nt<0><<<dim3(VOCAB / 64, M / 128), 256, 0, stream>>>(y2, Wlin, blin, nullptr,
                                                              logits, M, VOCAB, HID);
}